// Round 8
// baseline (5142.064 us; speedup 1.0000x reference)
//
#include <hip/hip_runtime.h>

#define BATCH 128
#define NUSERS 50000

typedef __attribute__((ext_vector_type(2))) float f32x2;

// ---------------- histogram ----------------
__global__ void hist_k(const int* __restrict__ keys, int* __restrict__ hist, int nnz) {
  int i = blockIdx.x * blockDim.x + threadIdx.x;
  int st = gridDim.x * blockDim.x;
  for (; i < nnz; i += st) atomicAdd(&hist[keys[i]], 1);
}

// ---------------- exclusive scan (single block, 1024 threads) ----------------
__global__ void scan_k(const int* __restrict__ hist, int* __restrict__ offs,
                       int* __restrict__ cursor, int n) {
  __shared__ int wsum[16];
  __shared__ int carry;
  int tid = threadIdx.x;
  int lane = tid & 63;
  int wv = tid >> 6;
  if (tid == 0) carry = 0;
  __syncthreads();
  for (int base = 0; base < n; base += 1024) {
    int i = base + tid;
    int x = (i < n) ? hist[i] : 0;
    int incl = x;
#pragma unroll
    for (int d = 1; d < 64; d <<= 1) {
      int y = __shfl_up(incl, (unsigned)d, 64);
      if (lane >= d) incl += y;
    }
    if (lane == 63) wsum[wv] = incl;
    __syncthreads();
    if (wv == 0) {
      int t = (lane < 16) ? wsum[lane] : 0;
#pragma unroll
      for (int d = 1; d < 16; d <<= 1) {
        int y = __shfl_up(t, (unsigned)d, 64);
        if (lane >= d) t += y;
      }
      if (lane < 16) wsum[lane] = t;
    }
    __syncthreads();
    int woff = (wv > 0) ? wsum[wv - 1] : 0;
    int excl = carry + woff + incl - x;
    if (i < n) { offs[i] = excl; cursor[i] = excl; }
    int chunk_total = wsum[15];
    __syncthreads();
    if (tid == 0) carry += chunk_total;
    __syncthreads();
  }
  if (tid == 0) offs[n] = carry;
}

// ---------------- cursor reinit ----------------
__global__ void reinit_cursor_k(const int* __restrict__ offs, int* __restrict__ cursor, int n) {
  int i = blockIdx.x * blockDim.x + threadIdx.x;
  if (i < n) cursor[i] = offs[i];
}

// ---------------- scatter 1: original COO -> CSC_tmp (key=col), random order ----------------
__global__ void scatter1_k(const int* __restrict__ rows, const int* __restrict__ cols,
                           const float* __restrict__ vals, int* __restrict__ cursor,
                           int2* __restrict__ out_ev, int* __restrict__ keycomp, int nnz) {
  int i = blockIdx.x * blockDim.x + threadIdx.x;
  int st = gridDim.x * blockDim.x;
  for (; i < nnz; i += st) {
    int c = cols[i];
    int p = atomicAdd(&cursor[c], 1);
    out_ev[p] = make_int2(rows[i], __float_as_int(vals[i]));
    keycomp[p] = c;
  }
}

// ---------------- scatter 2/3: re-sort pass ----------------
__global__ void rescatter_k(const int2* __restrict__ in_ev, const int* __restrict__ in_comp,
                            int* __restrict__ cursor, int2* __restrict__ out_ev,
                            int* __restrict__ out_comp, int nnz) {
  int i = blockIdx.x * blockDim.x + threadIdx.x;
  int st = gridDim.x * blockDim.x;
  for (; i < nnz; i += st) {
    int2 e = in_ev[i];        // e.x = key for this pass
    int q = atomicAdd(&cursor[e.x], 1);
    out_ev[q] = make_int2(in_comp[i], e.y);
    if (out_comp) out_comp[q] = e.x;
  }
}

// ---------------- T0 = Xb^T, acc = c0*T0 ----------------
__global__ void transpose_init_k(const float* __restrict__ Xb, const float* __restrict__ coeffs,
                                 float* __restrict__ T0, float* __restrict__ acc, int nitems) {
  __shared__ float tile[32][33];
  int tx = threadIdx.x, ty = threadIdx.y;
  int i0 = blockIdx.x * 32, b0 = blockIdx.y * 32;
#pragma unroll
  for (int j = 0; j < 4; j++) {
    int b = b0 + ty + j * 8;
    tile[ty + j * 8][tx] = Xb[(size_t)b * nitems + i0 + tx];
  }
  __syncthreads();
  float c0 = coeffs[0];
#pragma unroll
  for (int j = 0; j < 4; j++) {
    int il = ty + j * 8;
    float v = tile[tx][il];
    size_t idx = (size_t)(i0 + il) * BATCH + b0 + tx;
    T0[idx] = v;
    acc[idx] = c0 * v;
  }
}

// ---------------- out = acc^T ----------------
__global__ void transpose_out_k(const float* __restrict__ acc, float* __restrict__ out, int nitems) {
  __shared__ float tile[32][33];
  int tx = threadIdx.x, ty = threadIdx.y;
  int i0 = blockIdx.x * 32, b0 = blockIdx.y * 32;
#pragma unroll
  for (int j = 0; j < 4; j++) {
    int il = ty + j * 8;
    tile[il][tx] = acc[(size_t)(i0 + il) * BATCH + b0 + tx];
  }
  __syncthreads();
#pragma unroll
  for (int j = 0; j < 4; j++) {
    int bl = ty + j * 8;
    out[(size_t)(b0 + bl) * nitems + i0 + tx] = tile[tx][bl];
  }
}

// 8 independent 512B gathers in ONE asm block: compiler cannot re-serialize.
// Outputs valid on block exit (vmcnt(0) inside).
#define GATHER8(SRC)                                                          \
  {                                                                           \
    const float* p0 = SRC + ((size_t)e[0].x << 7) + co;                       \
    const float* p1 = SRC + ((size_t)e[1].x << 7) + co;                       \
    const float* p2 = SRC + ((size_t)e[2].x << 7) + co;                       \
    const float* p3 = SRC + ((size_t)e[3].x << 7) + co;                       \
    const float* p4 = SRC + ((size_t)e[4].x << 7) + co;                       \
    const float* p5 = SRC + ((size_t)e[5].x << 7) + co;                       \
    const float* p6 = SRC + ((size_t)e[6].x << 7) + co;                       \
    const float* p7 = SRC + ((size_t)e[7].x << 7) + co;                       \
    asm volatile(                                                             \
        "global_load_dwordx2 %0, %8, off\n\t"                                 \
        "global_load_dwordx2 %1, %9, off\n\t"                                 \
        "global_load_dwordx2 %2, %10, off\n\t"                                \
        "global_load_dwordx2 %3, %11, off\n\t"                                \
        "global_load_dwordx2 %4, %12, off\n\t"                                \
        "global_load_dwordx2 %5, %13, off\n\t"                                \
        "global_load_dwordx2 %6, %14, off\n\t"                                \
        "global_load_dwordx2 %7, %15, off\n\t"                                \
        "s_waitcnt vmcnt(0)"                                                  \
        : "=&v"(x0), "=&v"(x1), "=&v"(x2), "=&v"(x3), "=&v"(x4), "=&v"(x5),   \
          "=&v"(x6), "=&v"(x7)                                                \
        : "v"(p0), "v"(p1), "v"(p2), "v"(p3), "v"(p4), "v"(p5), "v"(p6),      \
          "v"(p7));                                                           \
  }

#define FMA8()                                                                \
  {                                                                           \
    float w0 = __int_as_float(e[0].y), w1 = __int_as_float(e[1].y);           \
    float w2 = __int_as_float(e[2].y), w3 = __int_as_float(e[3].y);           \
    float w4 = __int_as_float(e[4].y), w5 = __int_as_float(e[5].y);           \
    float w6 = __int_as_float(e[6].y), w7 = __int_as_float(e[7].y);           \
    a0.x = fmaf(w0, x0.x, a0.x); a0.y = fmaf(w0, x0.y, a0.y);                 \
    a1.x = fmaf(w1, x1.x, a1.x); a1.y = fmaf(w1, x1.y, a1.y);                 \
    a2.x = fmaf(w2, x2.x, a2.x); a2.y = fmaf(w2, x2.y, a2.y);                 \
    a3.x = fmaf(w3, x3.x, a3.x); a3.y = fmaf(w3, x3.y, a3.y);                 \
    a0.x = fmaf(w4, x4.x, a0.x); a0.y = fmaf(w4, x4.y, a0.y);                 \
    a1.x = fmaf(w5, x5.x, a1.x); a1.y = fmaf(w5, x5.y, a1.y);                 \
    a2.x = fmaf(w6, x6.x, a2.x); a2.y = fmaf(w6, x6.y, a2.y);                 \
    a3.x = fmaf(w7, x7.x, a3.x); a3.y = fmaf(w7, x7.y, a3.y);                 \
  }

// ---------------- phase A: u = X * v  (CSR over users) ----------------
__global__ void __launch_bounds__(256) spmm_u_k(const int* __restrict__ offs,
                                                const int2* __restrict__ ev,
                                                const float* __restrict__ v,
                                                float* __restrict__ u, int nrows) {
  int wid = __builtin_amdgcn_readfirstlane(threadIdx.x >> 6);
  int row = (blockIdx.x << 2) | wid;
  if (row >= nrows) return;
  int lane = threadIdx.x & 63;
  int co = lane << 1;
  int k0 = offs[row], k1 = offs[row + 1];
  float2 a0 = {0.f, 0.f}, a1 = {0.f, 0.f}, a2 = {0.f, 0.f}, a3 = {0.f, 0.f};
  int k = k0;
  for (; k + 8 <= k1; k += 8) {
    int2 e[8];
#pragma unroll
    for (int j = 0; j < 8; j++) e[j] = ev[k + j];
    f32x2 x0, x1, x2, x3, x4, x5, x6, x7;
    GATHER8(v)
    FMA8()
  }
  for (; k < k1; ++k) {
    int2 e = ev[k];
    float2 x = *reinterpret_cast<const float2*>(v + ((size_t)e.x << 7) + co);
    float w = __int_as_float(e.y);
    a0.x = fmaf(w, x.x, a0.x); a0.y = fmaf(w, x.y, a0.y);
  }
  float2 s;
  s.x = (a0.x + a1.x) + (a2.x + a3.x);
  s.y = (a0.y + a1.y) + (a2.y + a3.y);
  *reinterpret_cast<float2*>(u + ((size_t)row << 7) + co) = s;
}

// ---------------- phase B: w = X^T * u, fused Chebyshev update ----------------
__global__ void __launch_bounds__(256) spmm_i_cheb_k(const int* __restrict__ offs,
                                                     const int2* __restrict__ ev,
                                                     const float* __restrict__ u,
                                                     const float* __restrict__ vcur,
                                                     float* __restrict__ tio,
                                                     float* __restrict__ acc,
                                                     const float* __restrict__ t_mid,
                                                     const float* __restrict__ t_half,
                                                     const float* __restrict__ coeffs,
                                                     int cix, float sA, float sB, int nitems) {
  int wid = __builtin_amdgcn_readfirstlane(threadIdx.x >> 6);
  int item = (blockIdx.x << 2) | wid;
  if (item >= nitems) return;
  int lane = threadIdx.x & 63;
  int co = lane << 1;
  int k0 = offs[item], k1 = offs[item + 1];
  float2 a0 = {0.f, 0.f}, a1 = {0.f, 0.f}, a2 = {0.f, 0.f}, a3 = {0.f, 0.f};
  int k = k0;
  for (; k + 8 <= k1; k += 8) {
    int2 e[8];
#pragma unroll
    for (int j = 0; j < 8; j++) e[j] = ev[k + j];
    f32x2 x0, x1, x2, x3, x4, x5, x6, x7;
    GATHER8(u)
    FMA8()
  }
  for (; k < k1; ++k) {
    int2 e = ev[k];
    float2 x = *reinterpret_cast<const float2*>(u + ((size_t)e.x << 7) + co);
    float w = __int_as_float(e.y);
    a0.x = fmaf(w, x.x, a0.x); a0.y = fmaf(w, x.y, a0.y);
  }
  float2 w;
  w.x = (a0.x + a1.x) + (a2.x + a3.x);
  w.y = (a0.y + a1.y) + (a2.y + a3.y);

  float mid = t_mid[0];
  float inv = 1.0f / t_half[0];
  float c = coeffs[cix];
  size_t idx = ((size_t)item << 7) + co;
  float2 vv = *reinterpret_cast<const float2*>(vcur + idx);
  float2 t;
  t.x = (w.x - mid * vv.x) * inv;
  t.y = (w.y - mid * vv.y) * inv;
  if (sB != 0.0f) {
    float2 p = *reinterpret_cast<const float2*>(tio + idx);
    t.x = sA * t.x - sB * p.x;
    t.y = sA * t.y - sB * p.y;
  }
  *reinterpret_cast<float2*>(tio + idx) = t;
  float2 a = *reinterpret_cast<const float2*>(acc + idx);
  a.x = fmaf(c, t.x, a.x);
  a.y = fmaf(c, t.y, a.y);
  *reinterpret_cast<float2*>(acc + idx) = a;
}

extern "C" void kernel_launch(void* const* d_in, const int* in_sizes, int n_in,
                              void* d_out, int out_size, void* d_ws, size_t ws_size,
                              hipStream_t stream) {
  const float* Xb     = (const float*)d_in[0];
  const float* vals   = (const float*)d_in[1];
  const float* coeffs = (const float*)d_in[2];
  const float* t_mid  = (const float*)d_in[3];
  const float* t_half = (const float*)d_in[4];
  const int*   rows   = (const int*)d_in[5];
  const int*   cols   = (const int*)d_in[6];

  int nnz    = in_sizes[1];
  int nitems = in_sizes[0] / BATCH;   // 20000
  int nusers = NUSERS;                // 50000
  int ncoef  = in_sizes[2];           // 21

  char* base = (char*)d_ws;
  size_t o = 0;
  auto alloc = [&](size_t bytes) -> void* {
    void* p = base + o;
    o = (o + bytes + 255) & ~(size_t)255;
    return p;
  };
  // csc_tmp (setup only) aliases csc_ev (iteration): scatter3 writes it last.
  int2*  csc_ev   = (int2*)alloc((size_t)nnz * 8);   // final CSC (rows ~ascending within col)
  int2*  csr_ev   = (int2*)alloc((size_t)nnz * 8);   // final CSR (cols ~ascending within row)
  int*   csr_offs = (int*)alloc((size_t)(nusers + 1) * 4);
  int*   csc_offs = (int*)alloc((size_t)(nitems + 1) * 4);
  int*   cursor   = (int*)alloc((size_t)(nusers + 1) * 4);
  int*   hist     = (int*)alloc((size_t)(nusers + 1) * 4);
  float* u        = (float*)alloc((size_t)nusers * BATCH * 4);
  float* Ta       = (float*)alloc((size_t)nitems * BATCH * 4);
  float* Tb       = (float*)alloc((size_t)nitems * BATCH * 4);
  float* accb     = (float*)alloc((size_t)nitems * BATCH * 4);
  (void)ws_size;
  // setup-only temporaries living in u's space (u untouched until iterations)
  int* comp_a = (int*)u;                       // nnz ints (8 MB)
  int* comp_b = ((int*)u) + nnz;               // nnz ints (8 MB) -- u is 25.6 MB total

  // --- stage 1: COO -> csc_tmp (key=col), random within-col order ---
  hipMemsetAsync(hist, 0, (size_t)(nusers + 1) * 4, stream);
  hist_k<<<2048, 256, 0, stream>>>(cols, hist, nnz);
  scan_k<<<1, 1024, 0, stream>>>(hist, csc_offs, cursor, nitems);
  int2* csc_tmp = csc_ev;  // alias
  scatter1_k<<<2048, 256, 0, stream>>>(rows, cols, vals, cursor, csc_tmp, comp_a, nnz);
  // csc_tmp[p] = (row, val), comp_a[p] = col

  // --- stage 2: csc_tmp -> CSR (key=row); approx ascending col within row ---
  hipMemsetAsync(hist, 0, (size_t)(nusers + 1) * 4, stream);
  hist_k<<<2048, 256, 0, stream>>>(rows, hist, nnz);
  scan_k<<<1, 1024, 0, stream>>>(hist, csr_offs, cursor, nusers);
  rescatter_k<<<2048, 256, 0, stream>>>(csc_tmp, comp_a, cursor, csr_ev, comp_b, nnz);
  // csr_ev[q] = (col, val), comp_b[q] = row

  // --- stage 3: CSR -> CSC (key=col); approx ascending row within col ---
  reinit_cursor_k<<<(nitems + 255) / 256, 256, 0, stream>>>(csc_offs, cursor, nitems);
  rescatter_k<<<2048, 256, 0, stream>>>(csr_ev, comp_b, cursor, csc_ev, (int*)nullptr, nnz);
  // csc_ev[p] = (row, val)

  // T0 = Xb^T ; acc = c0*T0
  dim3 tb(32, 8);
  transpose_init_k<<<dim3(nitems / 32, BATCH / 32), tb, 0, stream>>>(Xb, coeffs, Ta, accb, nitems);

  int ublocks = (nusers + 3) / 4;
  int iblocks = (nitems + 3) / 4;

  // s = 1 : T1 = S(T0), acc += c1*T1
  spmm_u_k<<<ublocks, 256, 0, stream>>>(csr_offs, csr_ev, Ta, u, nusers);
  spmm_i_cheb_k<<<iblocks, 256, 0, stream>>>(csc_offs, csc_ev, u, Ta, Tb, accb,
                                             t_mid, t_half, coeffs, 1, 1.0f, 0.0f, nitems);
  float* Tp = Ta;  // holds T_{s-2}
  float* Tc = Tb;  // holds T_{s-1}
  for (int s = 2; s < ncoef; ++s) {
    spmm_u_k<<<ublocks, 256, 0, stream>>>(csr_offs, csr_ev, Tc, u, nusers);
    spmm_i_cheb_k<<<iblocks, 256, 0, stream>>>(csc_offs, csc_ev, u, Tc, Tp, accb,
                                               t_mid, t_half, coeffs, s, 2.0f, 1.0f, nitems);
    float* tmp = Tp; Tp = Tc; Tc = tmp;
  }

  // out = acc^T
  transpose_out_k<<<dim3(nitems / 32, BATCH / 32), tb, 0, stream>>>(accb, (float*)d_out, nitems);
}

// Round 9
// 4896.313 us; speedup vs baseline: 1.0502x; 1.0502x over previous
//
#include <hip/hip_runtime.h>

#define BATCH 128
#define NUSERS 50000
#define PW 16   // plane width (cols per slice)
#define NSL 8   // slices

// ---------------- fused histogram (rows + cols in one pass) ----------------
__global__ void hist2_k(const int* __restrict__ rows, const int* __restrict__ cols,
                        int* __restrict__ histU, int* __restrict__ histI, int nnz) {
  int i = blockIdx.x * blockDim.x + threadIdx.x;
  int st = gridDim.x * blockDim.x;
  for (; i < nnz; i += st) {
    atomicAdd(&histU[rows[i]], 1);
    atomicAdd(&histI[cols[i]], 1);
  }
}

// ---------------- exclusive scan (single block, 1024 threads) ----------------
__global__ void scan_k(const int* __restrict__ hist, int* __restrict__ offs,
                       int* __restrict__ cursor, int n) {
  __shared__ int wsum[16];
  __shared__ int carry;
  int tid = threadIdx.x;
  int lane = tid & 63;
  int wv = tid >> 6;
  if (tid == 0) carry = 0;
  __syncthreads();
  for (int base = 0; base < n; base += 1024) {
    int i = base + tid;
    int x = (i < n) ? hist[i] : 0;
    int incl = x;
#pragma unroll
    for (int d = 1; d < 64; d <<= 1) {
      int y = __shfl_up(incl, (unsigned)d, 64);
      if (lane >= d) incl += y;
    }
    if (lane == 63) wsum[wv] = incl;
    __syncthreads();
    if (wv == 0) {
      int t = (lane < 16) ? wsum[lane] : 0;
#pragma unroll
      for (int d = 1; d < 16; d <<= 1) {
        int y = __shfl_up(t, (unsigned)d, 64);
        if (lane >= d) t += y;
      }
      if (lane < 16) wsum[lane] = t;
    }
    __syncthreads();
    int woff = (wv > 0) ? wsum[wv - 1] : 0;
    int excl = carry + woff + incl - x;
    if (i < n) { offs[i] = excl; cursor[i] = excl; }
    int chunk_total = wsum[15];
    __syncthreads();
    if (tid == 0) carry += chunk_total;
    __syncthreads();
  }
  if (tid == 0) offs[n] = carry;
}

// ---------------- fused dual scatter: COO -> CSR ev + CSC ev ----------------
__global__ void scatter2_k(const int* __restrict__ rows, const int* __restrict__ cols,
                           const float* __restrict__ vals, int* __restrict__ curU,
                           int* __restrict__ curI, int2* __restrict__ csr_ev,
                           int2* __restrict__ csc_ev, int nnz) {
  int i = blockIdx.x * blockDim.x + threadIdx.x;
  int st = gridDim.x * blockDim.x;
  for (; i < nnz; i += st) {
    int r = rows[i], c = cols[i];
    int vb = __float_as_int(vals[i]);
    int p = atomicAdd(&curU[r], 1);
    csr_ev[p] = make_int2(c, vb);
    int q = atomicAdd(&curI[c], 1);
    csc_ev[q] = make_int2(r, vb);
  }
}

// ---------------- T0/acc init, plane-major: T0[p][item][16] ----------------
__global__ void transpose_init_k(const float* __restrict__ Xb, const float* __restrict__ coeffs,
                                 float* __restrict__ T0, float* __restrict__ acc, int nitems) {
  __shared__ float t[16][17];
  int tx = threadIdx.x, ty = threadIdx.y;
  int p = blockIdx.y;
  int i0 = blockIdx.x * 16;
  // b = p*16+ty, item = i0+tx : coalesced-ish 64B row reads
  t[ty][tx] = Xb[(size_t)(p * 16 + ty) * nitems + i0 + tx];
  __syncthreads();
  float c0 = coeffs[0];
  float v = t[tx][ty];  // (item=i0+ty, col-in-plane=tx)
  size_t o = (size_t)p * nitems * PW + (size_t)(i0 + ty) * PW + tx;
  T0[o] = v;
  acc[o] = c0 * v;
}

// ---------------- out[b][item] from acc planes ----------------
__global__ void transpose_out_k(const float* __restrict__ acc, float* __restrict__ out, int nitems) {
  __shared__ float t[16][17];
  int tx = threadIdx.x, ty = threadIdx.y;
  int p = blockIdx.y;
  int i0 = blockIdx.x * 16;
  t[ty][tx] = acc[(size_t)p * nitems * PW + (size_t)(i0 + ty) * PW + tx];  // item=i0+ty, col=tx
  __syncthreads();
  out[(size_t)(p * 16 + ty) * nitems + i0 + tx] = t[tx][ty];
}

// ---------------- phase A: u_plane[s] = X * v_plane[s] ----------------
// slice s = blockIdx & 7 (XCD round-robin); 8-lane slots, 32 rows/block;
// ev broadcast via shfl (1 load per 8 nnz per slot)
__global__ void __launch_bounds__(256) spmm_u_k(const int* __restrict__ offs,
                                                const int2* __restrict__ ev,
                                                const float* __restrict__ v,
                                                float* __restrict__ u,
                                                int nrows, size_t vstride, size_t ustride) {
  int s = blockIdx.x & 7;
  int g = blockIdx.x >> 3;
  int slot = threadIdx.x >> 3;
  int lane8 = threadIdx.x & 7;
  int row = g * 32 + slot;
  if (row >= nrows) return;
  int k0 = offs[row], k1 = offs[row + 1];
  const float* vp = v + (size_t)s * vstride + (lane8 << 1);
  float2 a = {0.f, 0.f};
  int base = threadIdx.x & ~7;
  for (int k = k0; k < k1; k += 8) {
    int kk = k + lane8;
    int2 e = (kk < k1) ? ev[kk] : make_int2(0, 0);
#pragma unroll
    for (int j = 0; j < 8; j++) {
      int src = base | j;
      int idx = __shfl(e.x, src);
      float w = __int_as_float(__shfl(e.y, src));
      float2 x = *reinterpret_cast<const float2*>(vp + ((size_t)idx << 4));
      a.x = fmaf(w, x.x, a.x);
      a.y = fmaf(w, x.y, a.y);
    }
  }
  *reinterpret_cast<float2*>(u + (size_t)s * ustride + ((size_t)row << 4) + (lane8 << 1)) = a;
}

// ---------------- phase B: w_plane[s] = X^T * u_plane[s]; fused Chebyshev ----------------
__global__ void __launch_bounds__(256) spmm_i_cheb_k(const int* __restrict__ offs,
                                                     const int2* __restrict__ ev,
                                                     const float* __restrict__ u,
                                                     const float* __restrict__ vcur,
                                                     float* __restrict__ tio,
                                                     float* __restrict__ acc,
                                                     const float* __restrict__ t_mid,
                                                     const float* __restrict__ t_half,
                                                     const float* __restrict__ coeffs,
                                                     int cix, float sA, float sB,
                                                     int nitems, size_t ustride, size_t tstride) {
  int s = blockIdx.x & 7;
  int g = blockIdx.x >> 3;
  int slot = threadIdx.x >> 3;
  int lane8 = threadIdx.x & 7;
  int item = g * 32 + slot;
  if (item >= nitems) return;
  int k0 = offs[item], k1 = offs[item + 1];
  const float* up = u + (size_t)s * ustride + (lane8 << 1);
  float2 w = {0.f, 0.f};
  int base = threadIdx.x & ~7;
  for (int k = k0; k < k1; k += 8) {
    int kk = k + lane8;
    int2 e = (kk < k1) ? ev[kk] : make_int2(0, 0);
#pragma unroll
    for (int j = 0; j < 8; j++) {
      int src = base | j;
      int idx = __shfl(e.x, src);
      float wv = __int_as_float(__shfl(e.y, src));
      float2 x = *reinterpret_cast<const float2*>(up + ((size_t)idx << 4));
      w.x = fmaf(wv, x.x, w.x);
      w.y = fmaf(wv, x.y, w.y);
    }
  }
  float mid = t_mid[0];
  float inv = 1.0f / t_half[0];
  float c = coeffs[cix];
  size_t idx = (size_t)s * tstride + ((size_t)item << 4) + (lane8 << 1);
  float2 vv = *reinterpret_cast<const float2*>(vcur + idx);
  float2 t;
  t.x = (w.x - mid * vv.x) * inv;
  t.y = (w.y - mid * vv.y) * inv;
  if (sB != 0.0f) {
    float2 p = *reinterpret_cast<const float2*>(tio + idx);
    t.x = sA * t.x - sB * p.x;
    t.y = sA * t.y - sB * p.y;
  }
  *reinterpret_cast<float2*>(tio + idx) = t;
  float2 a = *reinterpret_cast<const float2*>(acc + idx);
  a.x = fmaf(c, t.x, a.x);
  a.y = fmaf(c, t.y, a.y);
  *reinterpret_cast<float2*>(acc + idx) = a;
}

extern "C" void kernel_launch(void* const* d_in, const int* in_sizes, int n_in,
                              void* d_out, int out_size, void* d_ws, size_t ws_size,
                              hipStream_t stream) {
  const float* Xb     = (const float*)d_in[0];
  const float* vals   = (const float*)d_in[1];
  const float* coeffs = (const float*)d_in[2];
  const float* t_mid  = (const float*)d_in[3];
  const float* t_half = (const float*)d_in[4];
  const int*   rows   = (const int*)d_in[5];
  const int*   cols   = (const int*)d_in[6];

  int nnz    = in_sizes[1];
  int nitems = in_sizes[0] / BATCH;   // 20000
  int nusers = NUSERS;                // 50000
  int ncoef  = in_sizes[2];           // 21

  size_t vstride = (size_t)nitems * PW;   // plane stride for item-sided buffers
  size_t ustride = (size_t)nusers * PW;   // plane stride for u

  char* base = (char*)d_ws;
  size_t o = 0;
  auto alloc = [&](size_t bytes) -> void* {
    void* p = base + o;
    o = (o + bytes + 255) & ~(size_t)255;
    return p;
  };
  int2*  csr_ev   = (int2*)alloc((size_t)nnz * 8);
  int2*  csc_ev   = (int2*)alloc((size_t)nnz * 8);
  int*   csr_offs = (int*)alloc((size_t)(nusers + 1) * 4);
  int*   csc_offs = (int*)alloc((size_t)(nitems + 1) * 4);
  int*   curU     = (int*)alloc((size_t)(nusers + 1) * 4);
  int*   curI     = (int*)alloc((size_t)(nitems + 1) * 4);
  int*   histU    = (int*)alloc((size_t)(nusers + 1) * 4);
  int*   histI    = (int*)alloc((size_t)(nitems + 1) * 4);
  float* u        = (float*)alloc((size_t)NSL * ustride * 4);   // 25.6 MB
  float* Ta       = (float*)alloc((size_t)NSL * vstride * 4);   // 10.24 MB
  float* Tb       = (float*)alloc((size_t)NSL * vstride * 4);
  float* accb     = (float*)alloc((size_t)NSL * vstride * 4);
  (void)ws_size;

  // --- setup: fused hist, two scans, fused dual scatter ---
  hipMemsetAsync(histU, 0, (size_t)(nusers + 1) * 4, stream);
  hipMemsetAsync(histI, 0, (size_t)(nitems + 1) * 4, stream);
  hist2_k<<<2048, 256, 0, stream>>>(rows, cols, histU, histI, nnz);
  scan_k<<<1, 1024, 0, stream>>>(histU, csr_offs, curU, nusers);
  scan_k<<<1, 1024, 0, stream>>>(histI, csc_offs, curI, nitems);
  scatter2_k<<<2048, 256, 0, stream>>>(rows, cols, vals, curU, curI, csr_ev, csc_ev, nnz);

  // --- T0 planes + acc init ---
  dim3 tb16(16, 16);
  transpose_init_k<<<dim3(nitems / 16, BATCH / 16), tb16, 0, stream>>>(Xb, coeffs, Ta, accb, nitems);

  int ublocks = ((nusers + 31) / 32) * NSL;   // 1563*8
  int iblocks = ((nitems + 31) / 32) * NSL;   // 625*8

  // s = 1 : T1 = S(T0), acc += c1*T1
  spmm_u_k<<<ublocks, 256, 0, stream>>>(csr_offs, csr_ev, Ta, u, nusers, vstride, ustride);
  spmm_i_cheb_k<<<iblocks, 256, 0, stream>>>(csc_offs, csc_ev, u, Ta, Tb, accb,
                                             t_mid, t_half, coeffs, 1, 1.0f, 0.0f,
                                             nitems, ustride, vstride);
  float* Tp = Ta;  // T_{s-2}
  float* Tc = Tb;  // T_{s-1}
  for (int s = 2; s < ncoef; ++s) {
    spmm_u_k<<<ublocks, 256, 0, stream>>>(csr_offs, csr_ev, Tc, u, nusers, vstride, ustride);
    spmm_i_cheb_k<<<iblocks, 256, 0, stream>>>(csc_offs, csc_ev, u, Tc, Tp, accb,
                                               t_mid, t_half, coeffs, s, 2.0f, 1.0f,
                                               nitems, ustride, vstride);
    float* tmp = Tp; Tp = Tc; Tc = tmp;
  }

  // --- out = acc planes -> [batch][item] ---
  transpose_out_k<<<dim3(nitems / 16, BATCH / 16), tb16, 0, stream>>>(accb, (float*)d_out, nitems);
}